// Round 9
// baseline (1962.451 us; speedup 1.0000x reference)
//
#include <hip/hip_runtime.h>
#include <math.h>

#define B_ROWS 262144
#define GAMMA_C 1.3f
#define EPS_C 1e-5f
#define SQH_C 0.70710678118654752440f
#define SL_SCALE (1.0f/201326592.0f)   // 1/(3*B*256)

typedef _Float16 f16;
typedef f16 f16x8 __attribute__((ext_vector_type(8)));
typedef f16 f16x4 __attribute__((ext_vector_type(4)));
typedef float f32x4 __attribute__((ext_vector_type(4)));

__device__ __forceinline__ int SWZ(int row, int kb, int RB, int MSK) {
  return row * RB + (kb ^ ((row & MSK) << 4));
}

// ---------------- bn0 ----------------
__global__ void bn0_accum(const float* __restrict__ x, float* __restrict__ sums) {
  const int col = threadIdx.x;
  const size_t r0 = (size_t)blockIdx.x * 128;
  float s1 = 0.f, s2 = 0.f;
  for (int i = 0; i < 128; ++i) {
    float v = x[(r0 + i) * 256 + col];
    s1 += v; s2 += v * v;
  }
  atomicAdd(&sums[col * 2], s1);
  atomicAdd(&sums[col * 2 + 1], s2);
}

__global__ void bn0_final(const float* __restrict__ sums, const float* __restrict__ g,
                          const float* __restrict__ b, float* __restrict__ bnA,
                          float* __restrict__ bnB) {
  int c = threadIdx.x;
  float mu = sums[c * 2] * (1.f / B_ROWS);
  float var = sums[c * 2 + 1] * (1.f / B_ROWS) - mu * mu;
  float a = rsqrtf(var + EPS_C) * g[c];
  bnA[c] = a;
  bnB[c] = b[c] - mu * a;
}

// ---------------- combined weight prep: f32 [K][256] -> f16 [256][K], all weights ----------------
__global__ void wprep_all(const float* __restrict__ Wsh0, const float* __restrict__ Wsh1,
                          const float* __restrict__ Wstep, const float* __restrict__ Watt,
                          f16* __restrict__ wt_sh0, f16* __restrict__ wt_sh1,
                          f16* __restrict__ wt_step, f16* __restrict__ wt_att) {
  int b = blockIdx.x;
  const float* src; f16* dst; int K, lb;
  if (b < 256)       { src = Wsh0; dst = wt_sh0; K = 256; lb = b; }
  else if (b < 384)  { src = Wsh1; dst = wt_sh1; K = 128; lb = b - 256; }
  else if (b < 1152) { int i = (b - 384) >> 7; src = Wstep + i * 32768; dst = wt_step + i * 32768; K = 128; lb = (b - 384) & 127; }
  else               { int i = (b - 1152) >> 6; src = Watt + (size_t)(i + 1) * 16384; dst = wt_att + (size_t)(i + 1) * 16384; K = 64; lb = (b - 1152) & 63; }
  int idx = lb * 256 + threadIdx.x;
  int n = idx / K, k = idx - n * K;
  dst[idx] = (f16)src[(size_t)k * 256 + n];
}

// ---------------- m0: step-0 mask row (identical for all rows) ----------------
__global__ void m0_kernel(const float* __restrict__ ba, float* __restrict__ m0v,
                          float* __restrict__ prior1v, float* __restrict__ slpart) {
  const int l = threadIdx.x;       // 64 threads
  const int c0 = l << 2;
  float z[4];
#pragma unroll
  for (int j = 0; j < 4; ++j) z[j] = ba[c0 + j];
  float m = fmaxf(fmaxf(z[0], z[1]), fmaxf(z[2], z[3]));
#pragma unroll
  for (int d = 1; d < 64; d <<= 1) m = fmaxf(m, __shfl_xor(m, d));
  float lo = m - 1.f, hi = m;
  for (int it = 0; it < 24; ++it) {
    float tau = 0.5f * (lo + hi);
    float s = fmaxf(z[0] - tau, 0.f) + fmaxf(z[1] - tau, 0.f) +
              fmaxf(z[2] - tau, 0.f) + fmaxf(z[3] - tau, 0.f);
#pragma unroll
    for (int d = 1; d < 64; d <<= 1) s += __shfl_xor(s, d);
    if (s > 1.f) lo = tau; else hi = tau;
  }
  const float tau = 0.5f * (lo + hi);
  float ent = 0.f;
#pragma unroll
  for (int j = 0; j < 4; ++j) {
    float M = fmaxf(z[j] - tau, 0.f);
    m0v[c0 + j] = M;
    prior1v[c0 + j] = GAMMA_C - M;
    ent -= M * __logf(M + 1e-15f);
  }
#pragma unroll
  for (int d = 1; d < 64; d <<= 1) ent += __shfl_xor(ent, d);
  if (l == 0) slpart[512] = ent * (262144.f * SL_SCALE);
}

// ---------------- step-0 masks broadcast + Mx = m0 * x_bn ----------------
__global__ void mx0_kernel(const float* __restrict__ x, const float* __restrict__ m0v,
                           const float* __restrict__ bnA, const float* __restrict__ bnB,
                           float* __restrict__ mk, f16* __restrict__ Mx) {
  __shared__ float sm[256], sa[256], sb[256];
  const int tid = threadIdx.x;
  sm[tid] = m0v[tid]; sa[tid] = bnA[tid]; sb[tid] = bnB[tid];
  __syncthreads();
  const size_t r = (size_t)blockIdx.x * 8 + (tid >> 5);
  const int c0 = (tid & 31) << 3;
  const float* xp = x + r * 256 + c0;
  f32x4 x0 = *(const f32x4*)xp;
  f32x4 x1 = *(const f32x4*)(xp + 4);
  float* mp = mk + r * 256 + c0;   // masks region only 4B-aligned: scalar stores
  f16x8 mxv;
#pragma unroll
  for (int j = 0; j < 4; ++j) {
    mp[j] = sm[c0 + j];
    mp[4 + j] = sm[c0 + 4 + j];
    mxv[j] = (f16)(sm[c0 + j] * (x0[j] * sa[c0 + j] + sb[c0 + j]));
    mxv[4 + j] = (f16)(sm[c0 + 4 + j] * (x1[j] * sa[c0 + 4 + j] + sb[c0 + 4 + j]));
  }
  *(f16x8*)(Mx + r * 256 + c0) = mxv;
}

// ---------------- fused two-pass GEMM + ghost-BN + GLU ----------------
// COLUMN-SPLIT: 2 WGs per VB. WG(vb,half) computes gate pairs {half*64+i, half*64+128+i}, i<64,
// for all 1024 rows — stats self-contained per WG. 512 thr/WG, 8 waves, 2 WGs/CU.
template <int KD, int RESID, int DOUT>
__launch_bounds__(512, 4)
__global__ void fglu(const f16* __restrict__ Ag, const f16* __restrict__ Wt,
                     const float* __restrict__ gv, const float* __restrict__ bv,
                     f16* __restrict__ ho, float* __restrict__ dout, int s) {
  constexpr int KS = KD / 32;
  constexpr int RB = KD * 2;
  constexpr int MSK = (RB / 16 - 1) < 31 ? (RB / 16 - 1) : 31;
  constexpr int TPR = KD / 8;                 // staging threads per row
  constexpr int SPT = 64 * TPR / 512;         // f16x8 stores per thread (4 or 2)
  __shared__ __align__(16) f16 sA[64 * KD];
  __shared__ float sS1[256], sS2[256], sAf[128], sBf[128];
  char* sAc = (char*)sA;
  const int tid = threadIdx.x;
  const int w = tid >> 6, l = tid & 63, lg = l >> 4, lc = l & 15;
  const int mw = w >> 2, nw = w & 3;
  const int half = blockIdx.x & 1;
  const int r0 = (blockIdx.x >> 1) << 10;
  const int lc1 = nw * 16 + lc;               // [0,64) local col
  const int c1 = half * 64 + lc1;             // global gate-numerator col
  const int c2 = c1 + 128;                    // global gate-denominator col

  // hoist W fragments (col pair) into registers — reused by both passes
  f16x8 bf0[KS], bf1[KS];
#pragma unroll
  for (int ks = 0; ks < KS; ++ks) {
    bf0[ks] = *(const f16x8*)(Wt + (size_t)c1 * KD + ks * 32 + lg * 8);
    bf1[ks] = *(const f16x8*)(Wt + (size_t)c2 * KD + ks * 32 + lg * 8);
  }

  f16x8 pv[SPT];
  auto LDA = [&](int ch) {
#pragma unroll
    for (int p = 0; p < SPT; ++p) {
      int flat = p * 512 + tid;
      int row = flat / TPR, kc = flat % TPR;
      pv[p] = *(const f16x8*)(Ag + (size_t)(r0 + ch * 64 + row) * KD + kc * 8);
    }
  };
  auto STA = [&]() {
#pragma unroll
    for (int p = 0; p < SPT; ++p) {
      int flat = p * 512 + tid;
      int row = flat / TPR, kc = flat % TPR;
      *(f16x8*)(sAc + SWZ(row, kc * 16, RB, MSK)) = pv[p];
    }
  };

  // ---------------- pass 0: stats ----------------
  float st1a = 0.f, st2a = 0.f, st1b = 0.f, st2b = 0.f;
  LDA(0);
  for (int ch = 0; ch < 16; ++ch) {
    __syncthreads();
    STA();
    __syncthreads();
    if (ch < 15) LDA(ch + 1);
#pragma unroll
    for (int mt = 0; mt < 2; ++mt) {
      f32x4 a0 = {0.f,0.f,0.f,0.f}, a1 = {0.f,0.f,0.f,0.f};
      const int ar = mw * 32 + mt * 16 + lc;
#pragma unroll
      for (int ks = 0; ks < KS; ++ks) {
        f16x8 af = *(const f16x8*)(sAc + SWZ(ar, ks * 64 + lg * 16, RB, MSK));
        a0 = __builtin_amdgcn_mfma_f32_16x16x32_f16(af, bf0[ks], a0, 0, 0, 0);
        a1 = __builtin_amdgcn_mfma_f32_16x16x32_f16(af, bf1[ks], a1, 0, 0, 0);
      }
#pragma unroll
      for (int j = 0; j < 4; ++j) {
        st1a += a0[j]; st2a += a0[j] * a0[j];
        st1b += a1[j]; st2b += a1[j] * a1[j];
      }
    }
  }
  st1a += __shfl_xor(st1a, 16); st1a += __shfl_xor(st1a, 32);
  st2a += __shfl_xor(st2a, 16); st2a += __shfl_xor(st2a, 32);
  st1b += __shfl_xor(st1b, 16); st1b += __shfl_xor(st1b, 32);
  st2b += __shfl_xor(st2b, 16); st2b += __shfl_xor(st2b, 32);
  if (l < 16) {
    sS1[mw * 128 + lc1] = st1a;      sS2[mw * 128 + lc1] = st2a;
    sS1[mw * 128 + 64 + lc1] = st1b; sS2[mw * 128 + 64 + lc1] = st2b;
  }
  __syncthreads();
  if (tid < 128) {
    float s1 = sS1[tid] + sS1[128 + tid];
    float s2 = sS2[tid] + sS2[128 + tid];
    int gcol = half * 64 + (tid < 64 ? tid : tid + 64);
    float mu = s1 * (1.f / 1024.f);
    float var = s2 * (1.f / 1024.f) - mu * mu;
    float a = rsqrtf(var + EPS_C) * gv[gcol];
    sAf[tid] = a; sBf[tid] = bv[gcol] - mu * a;
  }
  __syncthreads();
  const float bA1 = sAf[lc1], bO1 = sBf[lc1];
  const float bA2 = sAf[64 + lc1], bO2 = sBf[64 + lc1];

  // ---------------- pass 1: apply (residual + dout in f32 at MFMA side) ----------------
  LDA(0);
  for (int ch = 0; ch < 16; ++ch) {
    __syncthreads();
    STA();
    __syncthreads();
    if (ch < 15) LDA(ch + 1);
#pragma unroll
    for (int mt = 0; mt < 2; ++mt) {
      f32x4 a0 = {0.f,0.f,0.f,0.f}, a1 = {0.f,0.f,0.f,0.f};
      const int ar = mw * 32 + mt * 16 + lc;
#pragma unroll
      for (int ks = 0; ks < KS; ++ks) {
        f16x8 af = *(const f16x8*)(sAc + SWZ(ar, ks * 64 + lg * 16, RB, MSK));
        a0 = __builtin_amdgcn_mfma_f32_16x16x32_f16(af, bf0[ks], a0, 0, 0, 0);
        a1 = __builtin_amdgcn_mfma_f32_16x16x32_f16(af, bf1[ks], a1, 0, 0, 0);
      }
#pragma unroll
      for (int j = 0; j < 4; ++j) {
        float g1 = a0[j] * bA1 + bO1;
        float g2 = a1[j] * bA2 + bO2;
        float hv = g1 / (1.f + __expf(-g2));
        const int rl = mw * 32 + mt * 16 + lg * 4 + j;
        if (RESID) {
          f16 hp = *(const f16*)(sAc + SWZ(rl, c1 * 2, RB, MSK));  // A-tile IS h_prev (KD=128)
          hv = (hv + (float)hp) * SQH_C;
        }
        if (DOUT && half == 0) {        // c1 < 64 exactly when half==0
          float rv = fmaxf(hv, 0.f);
          float* dp = dout + (size_t)(r0 + ch * 64 + rl) * 64 + c1;
          if (s == 0) *dp = rv; else *dp += rv;
        }
        ho[(size_t)(r0 + ch * 64 + rl) * 128 + c1] = (f16)hv;
      }
    }
  }
}

// ---------------- fused attention GEMM + ghost-BN + sparsemax + mask products ----------------
// SMODE 1: prior = broadcast vector, writes prior buffer. SMODE 2: prior = buffer, no write.
template <int SMODE>
__launch_bounds__(512)
__global__ void attmask(const f16* __restrict__ h1, const f16* __restrict__ Wt,
                        const float* __restrict__ ga, const float* __restrict__ ba,
                        const float* __restrict__ bnA, const float* __restrict__ bnB,
                        const float* __restrict__ prior1v, const f16* __restrict__ prin,
                        f16* __restrict__ prout, const float* __restrict__ x,
                        float* __restrict__ mk, f16* __restrict__ Mx,
                        float* __restrict__ slpart) {
  __shared__ f16 sW[256 * 64];
  __shared__ f16 sA[128 * 64];
  __shared__ float sS1[256], sS2[256], sAf[256], sBf[256], sbA[256], sbB[256], spv[256];
  __shared__ float sEnt[8];
  char* sWc = (char*)sW;
  char* sAc = (char*)sA;
  const int tid = threadIdx.x;
  const int vb = blockIdx.x;
  const int r0 = vb << 10;
  const int w = tid >> 6, l = tid & 63, lc = l & 15, lg = l >> 4;
  if (tid < 256) {
    sS1[tid] = 0.f; sS2[tid] = 0.f;
    sbA[tid] = bnA[tid]; sbB[tid] = bnB[tid];
    if (SMODE == 1) spv[tid] = prior1v[tid];
  }
#pragma unroll
  for (int it = 0; it < 4; ++it) {
    int flat = it * 512 + tid;
    int rw = flat >> 3, kc = flat & 7;
    *(f16x8*)(sWc + SWZ(rw, kc * 16, 128, 7)) = *(const f16x8*)(Wt + rw * 64 + kc * 8);
  }
  const int arow = tid >> 3, akc = tid & 7;
  const f16* aB = h1 + (size_t)(r0 + arow) * 128 + 64 + akc * 8;
  float ent = 0.f;

  for (int pass = 0; pass < 2; ++pass) {
    float st1[16], st2[16];
#pragma unroll
    for (int t = 0; t < 16; ++t) { st1[t] = 0.f; st2[t] = 0.f; }
    f16x8 pv0 = *(const f16x8*)(aB);
    f16x8 pv1 = *(const f16x8*)(aB + (size_t)64 * 128);
    for (int ch = 0; ch < 8; ++ch) {
      __syncthreads();
      *(f16x8*)(sAc + SWZ(arow, akc * 16, 128, 7)) = pv0;
      *(f16x8*)(sAc + SWZ(arow + 64, akc * 16, 128, 7)) = pv1;
      __syncthreads();
      if (ch + 1 < 8) {
        pv0 = *(const f16x8*)(aB + (size_t)(ch + 1) * 128 * 128);
        pv1 = *(const f16x8*)(aB + (size_t)((ch + 1) * 128 + 64) * 128);
      }
      f16x8 af0 = *(const f16x8*)(sAc + SWZ(w * 16 + lc, lg * 16, 128, 7));
      f16x8 af1 = *(const f16x8*)(sAc + SWZ(w * 16 + lc, 64 + lg * 16, 128, 7));
      const int rb = r0 + ch * 128 + w * 16;
      f32x4 z[16];
#pragma unroll
      for (int t = 0; t < 16; ++t) {
        f16x8 b0 = *(const f16x8*)(sWc + SWZ(t * 16 + lc, lg * 16, 128, 7));
        f16x8 b1 = *(const f16x8*)(sWc + SWZ(t * 16 + lc, 64 + lg * 16, 128, 7));
        f32x4 acc = {0.f, 0.f, 0.f, 0.f};
        acc = __builtin_amdgcn_mfma_f32_16x16x32_f16(af0, b0, acc, 0, 0, 0);
        acc = __builtin_amdgcn_mfma_f32_16x16x32_f16(af1, b1, acc, 0, 0, 0);
        if (pass == 0) {
          float s1 = 0.f, s2 = 0.f;
#pragma unroll
          for (int j = 0; j < 4; ++j) { float v = acc[j]; s1 += v; s2 += v * v; }
          st1[t] += s1; st2[t] += s2;
        } else {
          const int c = t * 16 + lc;
          const float a = sAf[c], bb = sBf[c];
#pragma unroll
          for (int j = 0; j < 4; ++j) {
            float pr;
            if (SMODE == 1) pr = spv[c];
            else pr = (float)prin[(size_t)(rb + lg * 4 + j) * 256 + c];
            z[t][j] = (acc[j] * a + bb) * pr;
          }
        }
      }
      if (pass == 1) {
        // in-register sparsemax for rows rb + lg*4 + {0..3}
        f32x4 mj, lo, hi;
#pragma unroll
        for (int j = 0; j < 4; ++j) {
          float m = z[0][j];
#pragma unroll
          for (int t = 1; t < 16; ++t) m = fmaxf(m, z[t][j]);
          mj[j] = m;
        }
#pragma unroll
        for (int d = 1; d < 16; d <<= 1)
#pragma unroll
          for (int j = 0; j < 4; ++j) mj[j] = fmaxf(mj[j], __shfl_xor(mj[j], d));
#pragma unroll
        for (int j = 0; j < 4; ++j) { lo[j] = mj[j] - 1.f; hi[j] = mj[j]; }
        for (int itb = 0; itb < 20; ++itb) {
          f32x4 tau, sv;
#pragma unroll
          for (int j = 0; j < 4; ++j) { tau[j] = 0.5f * (lo[j] + hi[j]); sv[j] = 0.f; }
#pragma unroll
          for (int t = 0; t < 16; ++t)
#pragma unroll
            for (int j = 0; j < 4; ++j) sv[j] += fmaxf(z[t][j] - tau[j], 0.f);
#pragma unroll
          for (int d = 1; d < 16; d <<= 1)
#pragma unroll
            for (int j = 0; j < 4; ++j) sv[j] += __shfl_xor(sv[j], d);
#pragma unroll
          for (int j = 0; j < 4; ++j) { if (sv[j] > 1.f) lo[j] = tau[j]; else hi[j] = tau[j]; }
        }
        f32x4 tau;
#pragma unroll
        for (int j = 0; j < 4; ++j) tau[j] = 0.5f * (lo[j] + hi[j]);
#pragma unroll
        for (int t = 0; t < 16; ++t) {
          const int c = t * 16 + lc;
#pragma unroll
          for (int j = 0; j < 4; ++j) {
            const size_t r = (size_t)(rb + lg * 4 + j);
            float Mv = fmaxf(z[t][j] - tau[j], 0.f);
            mk[r * 256 + c] = Mv;
            ent -= Mv * __logf(Mv + 1e-15f);
            float xb = x[r * 256 + c] * sbA[c] + sbB[c];
            Mx[r * 256 + c] = (f16)(Mv * xb);
            if (SMODE == 1) prout[r * 256 + c] = (f16)(spv[c] * (GAMMA_C - Mv));
          }
        }
      }
    }
    if (pass == 0) {
#pragma unroll
      for (int t = 0; t < 16; ++t) {
        float v1 = st1[t], v2 = st2[t];
        v1 += __shfl_xor(v1, 16); v2 += __shfl_xor(v2, 16);
        v1 += __shfl_xor(v1, 32); v2 += __shfl_xor(v2, 32);
        if (l < 16) {
          atomicAdd(&sS1[t * 16 + lc], v1);
          atomicAdd(&sS2[t * 16 + lc], v2);
        }
      }
      __syncthreads();
      if (tid < 256) {
        float mu = sS1[tid] * (1.f / 1024.f);
        float var = sS2[tid] * (1.f / 1024.f) - mu * mu;
        float a = rsqrtf(var + EPS_C) * ga[tid];
        sAf[tid] = a;
        sBf[tid] = ba[tid] - mu * a;
      }
      __syncthreads();
    }
  }
#pragma unroll
  for (int d = 1; d < 64; d <<= 1) ent += __shfl_xor(ent, d);
  if (l == 0) sEnt[w] = ent;
  __syncthreads();
  if (tid == 0) {
    float t = 0.f;
#pragma unroll
    for (int i = 0; i < 8; ++i) t += sEnt[i];
    slpart[(SMODE - 1) * 256 + vb] = t * SL_SCALE;
  }
}

__global__ void sl_reduce(const float* __restrict__ part, float* __restrict__ out, int n) {
  __shared__ float sm[256];
  float s = 0.f;
  for (int i = threadIdx.x; i < n; i += 256) s += part[i];
  sm[threadIdx.x] = s;
  __syncthreads();
  for (int d = 128; d > 0; d >>= 1) {
    if ((int)threadIdx.x < d) sm[threadIdx.x] += sm[threadIdx.x + d];
    __syncthreads();
  }
  if (threadIdx.x == 0) out[0] = sm[0];
}

// ---------------- host ----------------
extern "C" void kernel_launch(void* const* d_in, const int* in_sizes, int n_in,
                              void* d_out, int out_size, void* d_ws, size_t ws_size,
                              hipStream_t stream) {
  (void)in_sizes; (void)n_in; (void)out_size; (void)ws_size;
  const float* x    = (const float*)d_in[0];
  const float* bn0g = (const float*)d_in[1];
  const float* bn0b = (const float*)d_in[2];
  const float* Wsh0 = (const float*)d_in[3];
  const float* gsh0 = (const float*)d_in[4];
  const float* bsh0 = (const float*)d_in[5];
  const float* Wsh1 = (const float*)d_in[6];
  const float* gsh1 = (const float*)d_in[7];
  const float* bsh1 = (const float*)d_in[8];
  const float* Wstep = (const float*)d_in[9];
  const float* gstep = (const float*)d_in[10];
  const float* bstep = (const float*)d_in[11];
  const float* Watt = (const float*)d_in[12];
  const float* gatt = (const float*)d_in[13];
  const float* batt = (const float*)d_in[14];

  float* dout = (float*)d_out;
  float* slo = dout + (size_t)B_ROWS * 64;
  float* masks = slo + 1;

  char* ws = (char*)d_ws;
  size_t off = 0;
  auto carve = [&](size_t bytes) -> char* {
    char* p = ws + off;
    off += (bytes + 255) & ~(size_t)255;
    return p;
  };
  f16* wt_att   = (f16*)carve((size_t)3 * 256 * 64 * 2);
  f16* wt_sh0   = (f16*)carve((size_t)256 * 256 * 2);
  f16* wt_sh1   = (f16*)carve((size_t)256 * 128 * 2);
  f16* wt_step  = (f16*)carve((size_t)6 * 256 * 128 * 2);
  float* bn0sum = (float*)carve(512 * 4);
  float* bnA    = (float*)carve(256 * 4);
  float* bnB    = (float*)carve(256 * 4);
  float* m0v    = (float*)carve(256 * 4);
  float* prior1v= (float*)carve(256 * 4);
  float* slpart = (float*)carve(513 * 4);
  f16* prior    = (f16*)carve((size_t)B_ROWS * 256 * 2);
  f16* Mx       = (f16*)carve((size_t)B_ROWS * 256 * 2);
  f16* h0       = (f16*)carve((size_t)B_ROWS * 128 * 2);
  f16* h1       = (f16*)carve((size_t)B_ROWS * 128 * 2);

  // prep
  hipMemsetAsync(bn0sum, 0, 512 * 4, stream);
  bn0_accum<<<2048, 256, 0, stream>>>(x, bn0sum);
  bn0_final<<<1, 256, 0, stream>>>(bn0sum, bn0g, bn0b, bnA, bnB);
  wprep_all<<<1280, 256, 0, stream>>>(Wsh0, Wsh1, Wstep, Watt, wt_sh0, wt_sh1, wt_step, wt_att);
  m0_kernel<<<1, 64, 0, stream>>>(batt, m0v, prior1v, slpart);
  mx0_kernel<<<B_ROWS / 8, 256, 0, stream>>>(x, m0v, bnA, bnB, masks, Mx);

  for (int s = 0; s < 3; ++s) {
    if (s == 1)
      attmask<1><<<256, 512, 0, stream>>>(h1, wt_att + (size_t)1 * 256 * 64,
                                          gatt + 256, batt + 256, bnA, bnB,
                                          prior1v, nullptr, prior, x,
                                          masks + (size_t)1 * B_ROWS * 256, Mx, slpart);
    else if (s == 2)
      attmask<2><<<256, 512, 0, stream>>>(h1, wt_att + (size_t)2 * 256 * 64,
                                          gatt + 512, batt + 512, bnA, bnB,
                                          nullptr, prior, nullptr, x,
                                          masks + (size_t)2 * B_ROWS * 256, Mx, slpart);
    fglu<256, 0, 0><<<512, 512, 0, stream>>>(Mx, wt_sh0, gsh0, bsh0, h0, nullptr, s);
    fglu<128, 1, 0><<<512, 512, 0, stream>>>(h0, wt_sh1, gsh1, bsh1, h1, nullptr, s);
    fglu<128, 1, 0><<<512, 512, 0, stream>>>(h1, wt_step + (size_t)(s * 2 + 0) * 256 * 128,
                                             gstep + (s * 2 + 0) * 256, bstep + (s * 2 + 0) * 256,
                                             h0, nullptr, s);
    fglu<128, 1, 1><<<512, 512, 0, stream>>>(h0, wt_step + (size_t)(s * 2 + 1) * 256 * 128,
                                             gstep + (s * 2 + 1) * 256, bstep + (s * 2 + 1) * 256,
                                             h1, dout, s);
  }
  sl_reduce<<<1, 256, 0, stream>>>(slpart, slo, 513);
}